// Round 1
// baseline (811.726 us; speedup 1.0000x reference)
//
#include <hip/hip_runtime.h>
#include <hip/hip_bf16.h>
#include <math.h>

#define EMB 128
#define OUT 256
#define RAD 6
#define NDL 3
#define NTGT 12
#define MT 32          // nodes per fused block
#define S 264          // LDS activation stride (bf16 elems)

typedef __attribute__((ext_vector_type(8))) short short8;
typedef __attribute__((ext_vector_type(4))) float floatx4;

__device__ inline short f2bf(float x) {
    __hip_bfloat16 h = __float2bfloat16(x);
    return *reinterpret_cast<short*>(&h);
}

__device__ inline unsigned pack2bf(float x, float y) {
    unsigned a = (unsigned short)f2bf(x);
    unsigned b = (unsigned short)f2bf(y);
    return a | (b << 16);
}

// ---------------- CSR build ----------------

__global__ void hist_kernel(const int* __restrict__ src, int* __restrict__ counts, int E) {
    int i = blockIdx.x * blockDim.x + threadIdx.x;
    if (i < E) atomicAdd(&counts[src[i]], 1);
}

__global__ void scan_kernel(const int* __restrict__ counts, int* __restrict__ offs,
                            int* __restrict__ cursor, int N) {
    __shared__ int sums[1024];
    int tid = threadIdx.x;
    int chunk = (N + 1023) / 1024;
    int beg = tid * chunk;
    int end = min(beg + chunk, N);
    int s = 0;
    for (int i = beg; i < end; i++) s += counts[i];
    int mysum = s;
    sums[tid] = s;
    __syncthreads();
    for (int off = 1; off < 1024; off <<= 1) {
        int add = (tid >= off) ? sums[tid - off] : 0;
        __syncthreads();
        sums[tid] += add;
        __syncthreads();
    }
    int prefix = sums[tid] - mysum;
    for (int i = beg; i < end; i++) {
        int c = counts[i];
        offs[i] = prefix;
        cursor[i] = prefix;
        prefix += c;
    }
    if (tid == 0) offs[N] = sums[1023];
}

__global__ void scatter_kernel(const int* __restrict__ src, int* __restrict__ cursor,
                               int* __restrict__ eids, int E) {
    int i = blockIdx.x * blockDim.x + threadIdx.x;
    if (i < E) {
        int pos = atomicAdd(&cursor[src[i]], 1);
        eids[pos] = i;
    }
}

// ---------------- weight prep: bf16 + transpose ----------------

__global__ void prep_kernel(const float* __restrict__ w_up, const float* __restrict__ w_dense,
                            const float* __restrict__ w_final,
                            short* __restrict__ w_upT, short* __restrict__ w_dT,
                            short* __restrict__ w_fT) {
    const int T1 = OUT * EMB;
    const int T2 = NDL * OUT * OUT;
    const int T3 = 16 * OUT;
    int total = T1 + T2 + T3;
    for (int i = blockIdx.x * blockDim.x + threadIdx.x; i < total; i += gridDim.x * blockDim.x) {
        if (i < T1) {
            int n = i >> 7, k = i & 127;
            w_upT[i] = f2bf(w_up[k * OUT + n]);
        } else if (i < T1 + T2) {
            int j = i - T1;
            int l = j >> 16, o = (j >> 8) & 255, k = j & 255;
            w_dT[j] = f2bf(w_dense[(l << 16) + (k << 8) + o]);
        } else {
            int j = i - T1 - T2;
            int t = j >> 8, k = j & 255;
            w_fT[j] = (t < NTGT) ? f2bf(w_final[k * NTGT + t]) : (short)0;
        }
    }
}

// ---------------- fused gather + MLP chain + per-graph reduce ----------------
// Block = 256 threads = 4 waves, owns MT=32 nodes.
// Gather: each wave owns 8 node rows; lane owns cols 2*lane, 2*lane+1 (float2 m loads,
// full 512B coalesced row per wave). No cross-lane reduction, no staging syncs.
// Results packed to bf16 straight into sA[0], then the MFMA chain runs as before.

__global__ __launch_bounds__(256) void fused_kernel(
    const float* __restrict__ m, const float* __restrict__ rbf,
    const float* __restrict__ w_rbf,
    const int* __restrict__ offs, const int* __restrict__ eids,
    const short* __restrict__ w_upT, const short* __restrict__ w_dT,
    const float* __restrict__ b_dense, const short* __restrict__ w_fT,
    const int* __restrict__ node2graph, float* __restrict__ out, int N) {

    __shared__ short sA[2][MT * S];

    const int tid = threadIdx.x;
    const int n0 = blockIdx.x * MT;
    const int wave = tid >> 6, lane = tid & 63;
    const int lo = lane & 15;
    const int quad = lane >> 4;
    const int kq = quad * 8;
    const int wcol = wave * 64;

    // ----- gather phase -----
    float2 wq[RAD];
#pragma unroll
    for (int r = 0; r < RAD; r++) wq[r] = *(const float2*)&w_rbf[r * EMB + 2 * lane];

#pragma unroll 1
    for (int s = 0; s < 8; s++) {
        const int r = wave * 8 + s;
        const int n = n0 + r;
        float ax = 0.f, ay = 0.f;
        if (n < N) {
            const int b = offs[n], e = offs[n + 1];
            int i = b;
            for (; i + 4 <= e; i += 4) {
                int ev[4];
                float2 mv[4];
                float2 rv[4][3];
#pragma unroll
                for (int j = 0; j < 4; j++) ev[j] = eids[i + j];
#pragma unroll
                for (int j = 0; j < 4; j++) {
                    const float* rb = &rbf[(size_t)ev[j] * RAD];
                    rv[j][0] = *(const float2*)&rb[0];
                    rv[j][1] = *(const float2*)&rb[2];
                    rv[j][2] = *(const float2*)&rb[4];
                    mv[j] = *(const float2*)&m[(size_t)ev[j] * EMB + 2 * lane];
                }
#pragma unroll
                for (int j = 0; j < 4; j++) {
                    float cx = wq[0].x * rv[j][0].x + wq[1].x * rv[j][0].y
                             + wq[2].x * rv[j][1].x + wq[3].x * rv[j][1].y
                             + wq[4].x * rv[j][2].x + wq[5].x * rv[j][2].y;
                    float cy = wq[0].y * rv[j][0].x + wq[1].y * rv[j][0].y
                             + wq[2].y * rv[j][1].x + wq[3].y * rv[j][1].y
                             + wq[4].y * rv[j][2].x + wq[5].y * rv[j][2].y;
                    ax += mv[j].x * cx;
                    ay += mv[j].y * cy;
                }
            }
            for (; i < e; i++) {
                int e0 = eids[i];
                const float* rb = &rbf[(size_t)e0 * RAD];
                float2 p0 = *(const float2*)&rb[0];
                float2 p1 = *(const float2*)&rb[2];
                float2 p2 = *(const float2*)&rb[4];
                float2 m0 = *(const float2*)&m[(size_t)e0 * EMB + 2 * lane];
                float cx = wq[0].x * p0.x + wq[1].x * p0.y + wq[2].x * p1.x
                         + wq[3].x * p1.y + wq[4].x * p2.x + wq[5].x * p2.y;
                float cy = wq[0].y * p0.x + wq[1].y * p0.y + wq[2].y * p1.x
                         + wq[3].y * p1.y + wq[4].y * p2.x + wq[5].y * p2.y;
                ax += m0.x * cx;
                ay += m0.y * cy;
            }
        }
        *(unsigned*)&sA[0][r * S + 2 * lane] = pack2bf(ax, ay);
    }
    __syncthreads();

    // ----- MLP chain via MFMA -----
    auto layer = [&](int cur, int K, const short* __restrict__ Bt,
                     const float* __restrict__ bias, bool act) {
        floatx4 acc[2][4];
#pragma unroll
        for (int mt = 0; mt < 2; mt++)
#pragma unroll
            for (int nt = 0; nt < 4; nt++)
                acc[mt][nt] = floatx4{0.f, 0.f, 0.f, 0.f};

        for (int kc = 0; kc < K; kc += 32) {
            short8 a0 = *(const short8*)&sA[cur][(lo) * S + kc + kq];
            short8 a1 = *(const short8*)&sA[cur][(16 + lo) * S + kc + kq];
#pragma unroll
            for (int nt = 0; nt < 4; nt++) {
                int n = wcol + nt * 16 + lo;
                short8 b = *(const short8*)&Bt[(size_t)n * K + kc + kq];
                acc[0][nt] = __builtin_amdgcn_mfma_f32_16x16x32_bf16(a0, b, acc[0][nt], 0, 0, 0);
                acc[1][nt] = __builtin_amdgcn_mfma_f32_16x16x32_bf16(a1, b, acc[1][nt], 0, 0, 0);
            }
        }

        float bv[4];
#pragma unroll
        for (int nt = 0; nt < 4; nt++) bv[nt] = bias ? bias[wcol + nt * 16 + lo] : 0.f;

        short* dst = sA[cur ^ 1];
#pragma unroll
        for (int mt = 0; mt < 2; mt++)
#pragma unroll
            for (int nt = 0; nt < 4; nt++) {
                int n = wcol + nt * 16 + lo;
#pragma unroll
                for (int i = 0; i < 4; i++) {
                    int mrow = mt * 16 + quad * 4 + i;
                    float x = acc[mt][nt][i] + bv[nt];
                    if (act) x = x / (1.f + __expf(-x));
                    dst[mrow * S + n] = f2bf(x);
                }
            }
        __syncthreads();
    };

    layer(0, EMB, w_upT, nullptr, false);
    layer(1, OUT, w_dT + 0 * OUT * OUT, b_dense + 0 * OUT, true);
    layer(0, OUT, w_dT + 1 * OUT * OUT, b_dense + 1 * OUT, true);
    layer(1, OUT, w_dT + 2 * OUT * OUT, b_dense + 2 * OUT, true);

    if (wave == 0) {
        floatx4 facc[2];
        facc[0] = floatx4{0.f, 0.f, 0.f, 0.f};
        facc[1] = floatx4{0.f, 0.f, 0.f, 0.f};
        for (int kc = 0; kc < OUT; kc += 32) {
            short8 a0 = *(const short8*)&sA[0][(lo) * S + kc + kq];
            short8 a1 = *(const short8*)&sA[0][(16 + lo) * S + kc + kq];
            short8 b = *(const short8*)&w_fT[lo * OUT + kc + kq];
            facc[0] = __builtin_amdgcn_mfma_f32_16x16x32_bf16(a0, b, facc[0], 0, 0, 0);
            facc[1] = __builtin_amdgcn_mfma_f32_16x16x32_bf16(a1, b, facc[1], 0, 0, 0);
        }
        if (lo < NTGT) {
#pragma unroll
            for (int mt = 0; mt < 2; mt++)
#pragma unroll
                for (int i = 0; i < 4; i++) {
                    int node = n0 + mt * 16 + quad * 4 + i;
                    if (node < N)
                        atomicAdd(&out[node2graph[node] * NTGT + lo], facc[mt][i]);
                }
        }
    }
}

// ---------------- launch ----------------

extern "C" void kernel_launch(void* const* d_in, const int* in_sizes, int n_in,
                              void* d_out, int out_size, void* d_ws, size_t ws_size,
                              hipStream_t stream) {
    const float* m        = (const float*)d_in[0];
    const float* rbf      = (const float*)d_in[1];
    const int*   edge_src = (const int*)d_in[2];
    const int*   node2g   = (const int*)d_in[3];
    const float* w_rbf    = (const float*)d_in[4];
    const float* w_up     = (const float*)d_in[5];
    const float* w_dense  = (const float*)d_in[6];
    const float* b_dense  = (const float*)d_in[7];
    const float* w_final  = (const float*)d_in[8];

    int E = in_sizes[2];
    int N = in_sizes[3];
    float* out = (float*)d_out;

    char* p = (char*)d_ws;
    auto alloc = [&](size_t bytes) {
        char* r = p;
        p += (bytes + 255) & ~(size_t)255;
        return r;
    };
    int*   counts = (int*)alloc((size_t)N * 4);
    int*   offs   = (int*)alloc((size_t)(N + 1) * 4);
    int*   cursor = (int*)alloc((size_t)N * 4);
    int*   eids   = (int*)alloc((size_t)E * 4);
    short* w_upT  = (short*)alloc((size_t)OUT * EMB * 2);
    short* w_dT   = (short*)alloc((size_t)NDL * OUT * OUT * 2);
    short* w_fT   = (short*)alloc((size_t)16 * OUT * 2);

    hipMemsetAsync(counts, 0, (size_t)N * 4, stream);
    hipMemsetAsync(d_out, 0, (size_t)out_size * 4, stream);

    prep_kernel<<<512, 256, 0, stream>>>(w_up, w_dense, w_final, w_upT, w_dT, w_fT);
    hist_kernel<<<(E + 255) / 256, 256, 0, stream>>>(edge_src, counts, E);
    scan_kernel<<<1, 1024, 0, stream>>>(counts, offs, cursor, N);
    scatter_kernel<<<(E + 255) / 256, 256, 0, stream>>>(edge_src, cursor, eids, E);
    fused_kernel<<<(N + MT - 1) / MT, 256, 0, stream>>>(m, rbf, w_rbf, offs, eids,
                                                        w_upT, w_dT, b_dense, w_fT,
                                                        node2g, out, N);
}

// Round 2
// 779.696 us; speedup vs baseline: 1.0411x; 1.0411x over previous
//
#include <hip/hip_runtime.h>
#include <hip/hip_bf16.h>
#include <math.h>

#define EMB 128
#define OUT 256
#define RAD 6
#define NDL 3
#define NTGT 12
#define MT 32          // nodes per chain block
#define S 264          // LDS activation stride (bf16 elems)

typedef __attribute__((ext_vector_type(8))) short short8;
typedef __attribute__((ext_vector_type(4))) float floatx4;

__device__ inline short f2bf(float x) {
    __hip_bfloat16 h = __float2bfloat16(x);
    return *reinterpret_cast<short*>(&h);
}

__device__ inline unsigned pack2bf(float x, float y) {
    unsigned a = (unsigned short)f2bf(x);
    unsigned b = (unsigned short)f2bf(y);
    return a | (b << 16);
}

// ---------------- CSR build ----------------

__global__ void hist_kernel(const int* __restrict__ src, int* __restrict__ counts, int E) {
    int i = blockIdx.x * blockDim.x + threadIdx.x;
    if (i < E) atomicAdd(&counts[src[i]], 1);
}

__global__ void scan_kernel(const int* __restrict__ counts, int* __restrict__ offs,
                            int* __restrict__ cursor, int N) {
    __shared__ int sums[1024];
    int tid = threadIdx.x;
    int chunk = (N + 1023) / 1024;
    int beg = tid * chunk;
    int end = min(beg + chunk, N);
    int s = 0;
    for (int i = beg; i < end; i++) s += counts[i];
    int mysum = s;
    sums[tid] = s;
    __syncthreads();
    for (int off = 1; off < 1024; off <<= 1) {
        int add = (tid >= off) ? sums[tid - off] : 0;
        __syncthreads();
        sums[tid] += add;
        __syncthreads();
    }
    int prefix = sums[tid] - mysum;
    for (int i = beg; i < end; i++) {
        int c = counts[i];
        offs[i] = prefix;
        cursor[i] = prefix;
        prefix += c;
    }
    if (tid == 0) offs[N] = sums[1023];
}

__global__ void scatter_kernel(const int* __restrict__ src, int* __restrict__ cursor,
                               int* __restrict__ eids, int E) {
    int i = blockIdx.x * blockDim.x + threadIdx.x;
    if (i < E) {
        int pos = atomicAdd(&cursor[src[i]], 1);
        eids[pos] = i;
    }
}

// ---------------- weight prep: bf16 + transpose ----------------

__global__ void prep_kernel(const float* __restrict__ w_up, const float* __restrict__ w_dense,
                            const float* __restrict__ w_final,
                            short* __restrict__ w_upT, short* __restrict__ w_dT,
                            short* __restrict__ w_fT) {
    const int T1 = OUT * EMB;
    const int T2 = NDL * OUT * OUT;
    const int T3 = 16 * OUT;
    int total = T1 + T2 + T3;
    for (int i = blockIdx.x * blockDim.x + threadIdx.x; i < total; i += gridDim.x * blockDim.x) {
        if (i < T1) {
            int n = i >> 7, k = i & 127;
            w_upT[i] = f2bf(w_up[k * OUT + n]);
        } else if (i < T1 + T2) {
            int j = i - T1;
            int l = j >> 16, o = (j >> 8) & 255, k = j & 255;
            w_dT[j] = f2bf(w_dense[(l << 16) + (k << 8) + o]);
        } else {
            int j = i - T1 - T2;
            int t = j >> 8, k = j & 255;
            w_fT[j] = (t < NTGT) ? f2bf(w_final[k * NTGT + t]) : (short)0;
        }
    }
}

// ---------------- edge gather ----------------
// One block per node. 256 threads = 8 edge-groups x 32 col-lanes.
// Lane covers cols 4c..4c+3 (float4 m loads). Unroll 4 per group:
// 32 edges in flight per block, 4 independent float4 m-loads per lane
// issued before any math. No LDS eid staging (avg degree ~32).

__global__ __launch_bounds__(256) void gather_kernel(
    const float* __restrict__ m, const float* __restrict__ rbf,
    const float* __restrict__ w_rbf,
    const int* __restrict__ offs, const int* __restrict__ eids,
    __hip_bfloat16* __restrict__ t0, int N) {

    __shared__ float sRed[4][32][4];   // [wave][col-lane][comp]

    const int n = blockIdx.x;
    const int tid = threadIdx.x;
    const int g = tid >> 5;            // edge group 0..7
    const int c = tid & 31;            // col group -> cols 4c..4c+3
    const int wave = tid >> 6;

    float4 wq[RAD];
#pragma unroll
    for (int r = 0; r < RAD; r++) wq[r] = *(const float4*)&w_rbf[r * EMB + 4 * c];

    const int b = offs[n], e = offs[n + 1];
    float ax = 0.f, ay = 0.f, az = 0.f, aw = 0.f;

    int i = b + g;
    for (; i + 24 < e; i += 32) {
        int ev[4];
        ev[0] = eids[i];
        ev[1] = eids[i + 8];
        ev[2] = eids[i + 16];
        ev[3] = eids[i + 24];
        float2 rv[4][3];
        float4 mv[4];
#pragma unroll
        for (int j = 0; j < 4; j++) {
            const float* rb = &rbf[(size_t)ev[j] * RAD];
            rv[j][0] = *(const float2*)&rb[0];
            rv[j][1] = *(const float2*)&rb[2];
            rv[j][2] = *(const float2*)&rb[4];
            mv[j] = *(const float4*)&m[(size_t)ev[j] * EMB + 4 * c];
        }
#pragma unroll
        for (int j = 0; j < 4; j++) {
            float cx = wq[0].x * rv[j][0].x + wq[1].x * rv[j][0].y
                     + wq[2].x * rv[j][1].x + wq[3].x * rv[j][1].y
                     + wq[4].x * rv[j][2].x + wq[5].x * rv[j][2].y;
            float cy = wq[0].y * rv[j][0].x + wq[1].y * rv[j][0].y
                     + wq[2].y * rv[j][1].x + wq[3].y * rv[j][1].y
                     + wq[4].y * rv[j][2].x + wq[5].y * rv[j][2].y;
            float cz = wq[0].z * rv[j][0].x + wq[1].z * rv[j][0].y
                     + wq[2].z * rv[j][1].x + wq[3].z * rv[j][1].y
                     + wq[4].z * rv[j][2].x + wq[5].z * rv[j][2].y;
            float cw = wq[0].w * rv[j][0].x + wq[1].w * rv[j][0].y
                     + wq[2].w * rv[j][1].x + wq[3].w * rv[j][1].y
                     + wq[4].w * rv[j][2].x + wq[5].w * rv[j][2].y;
            ax += mv[j].x * cx;
            ay += mv[j].y * cy;
            az += mv[j].z * cz;
            aw += mv[j].w * cw;
        }
    }
    for (; i < e; i += 8) {
        int e0 = eids[i];
        const float* rb = &rbf[(size_t)e0 * RAD];
        float2 p0 = *(const float2*)&rb[0];
        float2 p1 = *(const float2*)&rb[2];
        float2 p2 = *(const float2*)&rb[4];
        float4 m0 = *(const float4*)&m[(size_t)e0 * EMB + 4 * c];
        float cx = wq[0].x * p0.x + wq[1].x * p0.y + wq[2].x * p1.x
                 + wq[3].x * p1.y + wq[4].x * p2.x + wq[5].x * p2.y;
        float cy = wq[0].y * p0.x + wq[1].y * p0.y + wq[2].y * p1.x
                 + wq[3].y * p1.y + wq[4].y * p2.x + wq[5].y * p2.y;
        float cz = wq[0].z * p0.x + wq[1].z * p0.y + wq[2].z * p1.x
                 + wq[3].z * p1.y + wq[4].z * p2.x + wq[5].z * p2.y;
        float cw = wq[0].w * p0.x + wq[1].w * p0.y + wq[2].w * p1.x
                 + wq[3].w * p1.y + wq[4].w * p2.x + wq[5].w * p2.y;
        ax += m0.x * cx;
        ay += m0.y * cy;
        az += m0.z * cz;
        aw += m0.w * cw;
    }

    // intra-wave: fold the wave's two edge-groups together
    ax += __shfl_xor(ax, 32);
    ay += __shfl_xor(ay, 32);
    az += __shfl_xor(az, 32);
    aw += __shfl_xor(aw, 32);

    // cross-wave via LDS (one b128 write per lane<32 of each wave)
    if ((tid & 63) < 32) {
        float4 v = {ax, ay, az, aw};
        *(float4*)&sRed[wave][c][0] = v;
    }
    __syncthreads();
    if (tid < 32) {
        float4 v0 = *(const float4*)&sRed[0][c][0];
        float4 v1 = *(const float4*)&sRed[1][c][0];
        float4 v2 = *(const float4*)&sRed[2][c][0];
        float4 v3 = *(const float4*)&sRed[3][c][0];
        float rx = v0.x + v1.x + v2.x + v3.x;
        float ry = v0.y + v1.y + v2.y + v3.y;
        float rz = v0.z + v1.z + v2.z + v3.z;
        float rw = v0.w + v1.w + v2.w + v3.w;
        unsigned lo = pack2bf(rx, ry);
        unsigned hi = pack2bf(rz, rw);
        uint2 pk = {lo, hi};
        *(uint2*)((short*)t0 + (size_t)n * EMB + 4 * c) = pk;
    }
}

// ---------------- node MLP chain via MFMA + per-graph reduce ----------------

__global__ __launch_bounds__(256) void chain_kernel(
    const __hip_bfloat16* __restrict__ t0,
    const short* __restrict__ w_upT, const short* __restrict__ w_dT,
    const float* __restrict__ b_dense, const short* __restrict__ w_fT,
    const int* __restrict__ node2graph, float* __restrict__ out, int N) {

    __shared__ short sA[2][MT * S];

    int tid = threadIdx.x;
    int n0 = blockIdx.x * MT;
    int wave = tid >> 6, lane = tid & 63;
    int lo = lane & 15;
    int quad = lane >> 4;
    int kq = quad * 8;
    int wcol = wave * 64;

    {
        int r = tid >> 3;
        int c = (tid & 7) * 16;
        uint4 v0 = {0, 0, 0, 0}, v1 = {0, 0, 0, 0};
        if (n0 + r < N) {
            const uint4* src = (const uint4*)((const short*)t0 + (size_t)(n0 + r) * EMB + c);
            v0 = src[0];
            v1 = src[1];
        }
        *(uint4*)&sA[0][r * S + c] = v0;
        *(uint4*)&sA[0][r * S + c + 8] = v1;
    }
    __syncthreads();

    auto layer = [&](int cur, int K, const short* __restrict__ Bt,
                     const float* __restrict__ bias, bool act) {
        floatx4 acc[2][4];
#pragma unroll
        for (int mt = 0; mt < 2; mt++)
#pragma unroll
            for (int nt = 0; nt < 4; nt++)
                acc[mt][nt] = floatx4{0.f, 0.f, 0.f, 0.f};

        for (int kc = 0; kc < K; kc += 32) {
            short8 a0 = *(const short8*)&sA[cur][(lo) * S + kc + kq];
            short8 a1 = *(const short8*)&sA[cur][(16 + lo) * S + kc + kq];
#pragma unroll
            for (int nt = 0; nt < 4; nt++) {
                int n = wcol + nt * 16 + lo;
                short8 b = *(const short8*)&Bt[(size_t)n * K + kc + kq];
                acc[0][nt] = __builtin_amdgcn_mfma_f32_16x16x32_bf16(a0, b, acc[0][nt], 0, 0, 0);
                acc[1][nt] = __builtin_amdgcn_mfma_f32_16x16x32_bf16(a1, b, acc[1][nt], 0, 0, 0);
            }
        }

        float bv[4];
#pragma unroll
        for (int nt = 0; nt < 4; nt++) bv[nt] = bias ? bias[wcol + nt * 16 + lo] : 0.f;

        short* dst = sA[cur ^ 1];
#pragma unroll
        for (int mt = 0; mt < 2; mt++)
#pragma unroll
            for (int nt = 0; nt < 4; nt++) {
                int n = wcol + nt * 16 + lo;
#pragma unroll
                for (int i = 0; i < 4; i++) {
                    int mrow = mt * 16 + quad * 4 + i;
                    float x = acc[mt][nt][i] + bv[nt];
                    if (act) x = x / (1.f + __expf(-x));
                    dst[mrow * S + n] = f2bf(x);
                }
            }
        __syncthreads();
    };

    layer(0, EMB, w_upT, nullptr, false);
    layer(1, OUT, w_dT + 0 * OUT * OUT, b_dense + 0 * OUT, true);
    layer(0, OUT, w_dT + 1 * OUT * OUT, b_dense + 1 * OUT, true);
    layer(1, OUT, w_dT + 2 * OUT * OUT, b_dense + 2 * OUT, true);

    if (wave == 0) {
        floatx4 facc[2];
        facc[0] = floatx4{0.f, 0.f, 0.f, 0.f};
        facc[1] = floatx4{0.f, 0.f, 0.f, 0.f};
        for (int kc = 0; kc < OUT; kc += 32) {
            short8 a0 = *(const short8*)&sA[0][(lo) * S + kc + kq];
            short8 a1 = *(const short8*)&sA[0][(16 + lo) * S + kc + kq];
            short8 b = *(const short8*)&w_fT[lo * OUT + kc + kq];
            facc[0] = __builtin_amdgcn_mfma_f32_16x16x32_bf16(a0, b, facc[0], 0, 0, 0);
            facc[1] = __builtin_amdgcn_mfma_f32_16x16x32_bf16(a1, b, facc[1], 0, 0, 0);
        }
        if (lo < NTGT) {
#pragma unroll
            for (int mt = 0; mt < 2; mt++)
#pragma unroll
                for (int i = 0; i < 4; i++) {
                    int node = n0 + mt * 16 + quad * 4 + i;
                    if (node < N)
                        atomicAdd(&out[node2graph[node] * NTGT + lo], facc[mt][i]);
                }
        }
    }
}

// ---------------- launch ----------------

extern "C" void kernel_launch(void* const* d_in, const int* in_sizes, int n_in,
                              void* d_out, int out_size, void* d_ws, size_t ws_size,
                              hipStream_t stream) {
    const float* m        = (const float*)d_in[0];
    const float* rbf      = (const float*)d_in[1];
    const int*   edge_src = (const int*)d_in[2];
    const int*   node2g   = (const int*)d_in[3];
    const float* w_rbf    = (const float*)d_in[4];
    const float* w_up     = (const float*)d_in[5];
    const float* w_dense  = (const float*)d_in[6];
    const float* b_dense  = (const float*)d_in[7];
    const float* w_final  = (const float*)d_in[8];

    int E = in_sizes[2];
    int N = in_sizes[3];
    float* out = (float*)d_out;

    char* p = (char*)d_ws;
    auto alloc = [&](size_t bytes) {
        char* r = p;
        p += (bytes + 255) & ~(size_t)255;
        return r;
    };
    int*   counts = (int*)alloc((size_t)N * 4);
    int*   offs   = (int*)alloc((size_t)(N + 1) * 4);
    int*   cursor = (int*)alloc((size_t)N * 4);
    int*   eids   = (int*)alloc((size_t)E * 4);
    __hip_bfloat16* t0 = (__hip_bfloat16*)alloc((size_t)N * EMB * 2);
    short* w_upT  = (short*)alloc((size_t)OUT * EMB * 2);
    short* w_dT   = (short*)alloc((size_t)NDL * OUT * OUT * 2);
    short* w_fT   = (short*)alloc((size_t)16 * OUT * 2);

    hipMemsetAsync(counts, 0, (size_t)N * 4, stream);
    hipMemsetAsync(d_out, 0, (size_t)out_size * 4, stream);

    prep_kernel<<<512, 256, 0, stream>>>(w_up, w_dense, w_final, w_upT, w_dT, w_fT);
    hist_kernel<<<(E + 255) / 256, 256, 0, stream>>>(edge_src, counts, E);
    scan_kernel<<<1, 1024, 0, stream>>>(counts, offs, cursor, N);
    scatter_kernel<<<(E + 255) / 256, 256, 0, stream>>>(edge_src, cursor, eids, E);
    gather_kernel<<<N, 256, 0, stream>>>(m, rbf, w_rbf, offs, eids, t0, N);
    chain_kernel<<<(N + MT - 1) / MT, 256, 0, stream>>>(t0, w_upT, w_dT, b_dense,
                                                        w_fT, node2g, out, N);
}